// Round 3
// baseline (101.798 us; speedup 1.0000x reference)
//
#include <hip/hip_runtime.h>

#define NTOK 32
#define PADT 1
#define MLEN 512
#define NLEN 1024
#define EPS_F 1e-7f
#define CCH 256            // columns per chunk
#define NC 4               // NLEN / CCH
#define NWAVE 4
#define BSTRIDE 416        // floats per boundary buffer (129 f2 slots used + prefetch pad)

// LDS layout (float offsets). nl placed LAST so negative stream underflow
// (up to -504B at lane 63) lands in the arrays below it (allocated, masked-unused).
#define OFF_BND   0
#define OFF_P0    (OFF_BND + 4*2*BSTRIDE)        // 3328
#define OFF_TOK   (OFF_P0 + 1184)                // 4512 (ints)
#define OFF_WTMP  (OFF_TOK + 512)                // 5024
#define OFF_NL    (OFF_WTMP + 16)                // 5040
#define LDS_FLOATS (OFF_NL + NTOK*NLEN + 160)    // tail pad for +142f overread

// One systolic iteration: 8 steps, each step = 2 cols x 2 rows per lane.
// State: s0 = V[r0][last col], s1 = V[r1][last col] (also DPP-passed), pA = V[r1][colA]
// (DPP-passed), dgA = V[r0-1][colA-1]. V[r][c] := D[r][c+1].
template <bool MASKED>
__device__ __forceinline__ void do_iter2(
    const float2*& q0, const float2*& q1, const float2*& qi, const float2*& qb,
    float2 (&C0)[8], float2 (&C1)[8], float2 (&CI)[8], float2 (&CB)[8],
    float2 (&N0)[8], float2 (&N1)[8], float2 (&NI)[8], float2 (&NB)[8],
    float& s0, float& s1, float& pA, float& dgA,
    int& sb, const int lane, float2* __restrict__ bw2)
{
#pragma unroll
  for (int k = 0; k < 8; ++k) {
    N0[k] = q0[8 + k]; N1[k] = q1[8 + k];
    NI[k] = qi[8 + k]; NB[k] = qb[8 + k];
  }
#pragma unroll
  for (int k = 0; k < 8; ++k) {
    // up values for row r0 at cols jA,jB come from lane-1's r1 results (prev step);
    // lane 0 injects the boundary stream via the DPP 'old' operand.
    float upA = __int_as_float(__builtin_amdgcn_update_dpp(
        __float_as_int(CB[k].x), __float_as_int(pA), 0x138, 0xF, 0xF, false));
    float upB = __int_as_float(__builtin_amdgcn_update_dpp(
        __float_as_int(CB[k].y), __float_as_int(s1), 0x138, 0xF, 0xF, false));
    float mA0 = fminf(fminf(dgA + C0[k].x, upA + 1.0f), s0 + CI[k].x);
    float mB0 = fminf(fminf(upA + C0[k].y, upB + 1.0f), mA0 + CI[k].y);
    float mA1 = fminf(fminf(s0  + C1[k].x, mA0 + 1.0f), s1 + CI[k].x);
    float mB1 = fminf(fminf(mA0 + C1[k].y, mB0 + 1.0f), mA1 + CI[k].y);
    if (lane == 63) {
      int sl = sb + k - 63;
      if (MASKED) sl = sl < 0 ? 0 : sl;   // early garbage lands on slot 0, overwritten at rsk==0
      bw2[sl] = make_float2(mA1, mB1);
    }
    if (MASKED) {
      int rsk = sb + k - lane;
      bool act = ((unsigned)rsk) < 128u;
      dgA = (rsk < 128) ? upB : dgA;      // updates during ramp-in (self-maintains boundary)
      s0 = act ? mB0 : s0;
      pA = act ? mA1 : pA;
      s1 = act ? mB1 : s1;
    } else {
      dgA = upB; s0 = mB0; pA = mA1; s1 = mB1;
    }
  }
  q0 += 8; q1 += 8; qi += 8; qb += 8; sb += 8;
}

__global__ __launch_bounds__(256, 1) void align_loss_kernel(
    const int* __restrict__ y_true, const float* __restrict__ y_pred,
    float* __restrict__ partial)
{
  extern __shared__ float smem[];
  float* bnd   = smem + OFF_BND;
  float* P0arr = smem + OFF_P0;
  int*   tok   = (int*)(smem + OFF_TOK);
  float* wtmp  = smem + OFF_WTMP;
  int*   wti   = (int*)wtmp;
  float* nl    = smem + OFF_NL;

  const int b = blockIdx.x;
  const int t = threadIdx.x;
  const int lane = t & 63;
  const int wv = t >> 6;

  // ---- Phase A: left-shift compaction (2 halves of 256) ----
  tok[t] = 0; tok[t + 256] = 0;
  __syncthreads();
  int total = 0;
  for (int h = 0; h < 2; ++h) {
    int yt = y_true[b * MLEN + h * 256 + t];
    bool f = (yt != PADT);
    unsigned long long m = __ballot(f);
    int wp = __popcll(m & ((1ull << lane) - 1ull));
    if (lane == 0) wti[8 + wv] = __popcll(m);
    __syncthreads();
    int offs = total, ht = 0;
#pragma unroll
    for (int w2 = 0; w2 < NWAVE; ++w2) { int cnt = wti[8 + w2]; if (w2 < wv) offs += cnt; ht += cnt; }
    if (f) tok[offs + wp] = yt;
    total += ht;
    __syncthreads();
  }
  const int L = total;

  // ---- Phase B: nl[tk][r] = -log(clip(y_pred[b,r,tk]/sum)) ----
  for (int r = t; r < NLEN; r += 256) {
    const float4* rp = (const float4*)(y_pred + ((size_t)b * NLEN + r) * NTOK);
    float4 q[8]; float s = 0.f;
#pragma unroll
    for (int u = 0; u < 8; ++u) { q[u] = rp[u]; s += q[u].x + q[u].y + q[u].z + q[u].w; }
    float inv = 1.0f / s;
#pragma unroll
    for (int u = 0; u < 8; ++u) {
      float pv[4] = {q[u].x, q[u].y, q[u].z, q[u].w};
#pragma unroll
      for (int c2 = 0; c2 < 4; ++c2) {
        float p = pv[c2] * inv;
        p = fminf(fmaxf(p, EPS_F), 1.0f - EPS_F);
        nl[(u * 4 + c2) * NLEN + r] = -__logf(p);
      }
    }
  }
  __syncthreads();

  // ---- Row-0 prefix: P0arr[m] = V[0][m] = sum_{r<=m} ins[r] ----
  {
    float4 iv = *(const float4*)(nl + PADT * NLEN + 4 * t);
    float p1 = iv.x, p2 = iv.x + iv.y, p3 = p2 + iv.z, s4 = p3 + iv.w;
    float x = s4;
#pragma unroll
    for (int d = 1; d < 64; d <<= 1) {
      float y = __shfl_up(x, d);
      if (lane >= d) x += y;
    }
    if (lane == 63) wtmp[wv] = x;
    __syncthreads();
    float pre = x - s4;
#pragma unroll
    for (int w2 = 0; w2 < NWAVE; ++w2) if (w2 < wv) pre += wtmp[w2];
    *(float4*)(P0arr + 4 * t) = make_float4(pre + p1, pre + p2, pre + p3, pre + s4);
  }

  // ---- DP state: lane owns rows r0 = 2t+1, r1 = 2t+2 ----
  const int r0 = 2 * t + 1;
  const int tk0 = tok[2 * t];
  const int tk1 = tok[2 * t + 1];
  const float* sub0 = nl + tk0 * NLEN;
  const float* sub1 = nl + tk1 * NLEN;
  const float* insp = nl + PADT * NLEN;
  float s0  = (float)r0;        // V[r0][-1] = D[r0][0]
  float s1  = (float)(r0 + 1);  // V[r1][-1]
  float dgA = (float)(r0 - 1);  // V[r0-1][-1]
  float pA  = (float)(r0 + 1);  // never consumed before first producer step

  // ---- Systolic chunk phases: 7 phases x 24 do_iters (192 steps = 128 active + skew) ----
  for (int p = 0; p < NC + NWAVE - 1; ++p) {
    __syncthreads();
    const int c = p - wv;
    if (c < 0 || c >= NC) continue;
    const int base = c * CCH;
    const float2* q0 = (const float2*)(sub0 + base) - lane;
    const float2* q1 = (const float2*)(sub1 + base) - lane;
    const float2* qi = (const float2*)(insp + base) - lane;
    const float2* qb = (wv == 0) ? (const float2*)(P0arr + base)
                                 : (const float2*)(bnd + ((wv - 1) * 2 + (p & 1)) * BSTRIDE);
    float2* bw2 = (float2*)(bnd + (wv * 2 + ((p + 1) & 1)) * BSTRIDE);

    float2 A0[8], A1[8], AI[8], AB[8], B0[8], B1[8], BI[8], BB[8];
#pragma unroll
    for (int k = 0; k < 8; ++k) { A0[k] = q0[k]; A1[k] = q1[k]; AI[k] = qi[k]; AB[k] = qb[k]; }
    int sb = 0;
    for (int it2 = 0; it2 < 4; ++it2) {  // ramp-in (masked), sb 0..63
      do_iter2<true>(q0, q1, qi, qb, A0, A1, AI, AB, B0, B1, BI, BB, s0, s1, pA, dgA, sb, lane, bw2);
      do_iter2<true>(q0, q1, qi, qb, B0, B1, BI, BB, A0, A1, AI, AB, s0, s1, pA, dgA, sb, lane, bw2);
    }
    for (int it2 = 0; it2 < 4; ++it2) {  // clean middle, sb 64..127
      do_iter2<false>(q0, q1, qi, qb, A0, A1, AI, AB, B0, B1, BI, BB, s0, s1, pA, dgA, sb, lane, bw2);
      do_iter2<false>(q0, q1, qi, qb, B0, B1, BI, BB, A0, A1, AI, AB, s0, s1, pA, dgA, sb, lane, bw2);
    }
    for (int it2 = 0; it2 < 4; ++it2) {  // ramp-out (masked), sb 128..191
      do_iter2<true>(q0, q1, qi, qb, A0, A1, AI, AB, B0, B1, BI, BB, s0, s1, pA, dgA, sb, lane, bw2);
      do_iter2<true>(q0, q1, qi, qb, B0, B1, BI, BB, A0, A1, AI, AB, s0, s1, pA, dgA, sb, lane, bw2);
    }
  }

  // ---- Extract D[L][NLEN]: s0/s1 hold V[r][1023] = D[r][1024] ----
  if (r0 == L) partial[b] = s0;
  if (r0 + 1 == L) partial[b] = s1;
  if (L == 0 && t == 0) partial[b] = P0arr[NLEN - 1];
}

__global__ void reduce_kernel(const float* __restrict__ partial, float* __restrict__ out) {
  if (threadIdx.x == 0) {
    float s = 0.f;
    for (int b2 = 0; b2 < 32; ++b2) s += partial[b2];
    out[0] = s;
  }
}

extern "C" void kernel_launch(void* const* d_in, const int* in_sizes, int n_in,
                              void* d_out, int out_size, void* d_ws, size_t ws_size,
                              hipStream_t stream) {
  const int*   y_true = (const int*)d_in[0];
  const float* y_pred = (const float*)d_in[1];
  float* out = (float*)d_out;
  float* partial = (float*)d_ws;

  const size_t lds_bytes = (size_t)LDS_FLOATS * sizeof(float);
  hipFuncSetAttribute((const void*)align_loss_kernel,
                      hipFuncAttributeMaxDynamicSharedMemorySize, (int)lds_bytes);

  hipLaunchKernelGGL(align_loss_kernel, dim3(32), dim3(256), lds_bytes, stream,
                     y_true, y_pred, partial);
  hipLaunchKernelGGL(reduce_kernel, dim3(1), dim3(64), 0, stream, partial, out);
}

// Round 4
// 97.521 us; speedup vs baseline: 1.0439x; 1.0439x over previous
//
#include <hip/hip_runtime.h>

#define NTOK 32
#define PADT 1
#define MLEN 512
#define NLEN 1024
#define EPS_F 1e-7f

#define RCH 128
#define NC  4
#define NWAVE 4
#define NPHASE (NC + NWAVE - 1)   // 7

// LDS float offsets
#define OFF_P0   0                        // P0[1024]: prefix sums of ins (V[0][j+1])
#define OFF_BND  1024                     // bnd[3 ifaces][2 parity][256]
#define OFF_BNDZ (OFF_BND + 6*256)        // 2560: wave-0 left boundary (row index values)
#define OFF_TOK  (OFF_BNDZ + 256)         // 2816: int tokbuf[64 guard + 512 + 160 guard]
#define OFF_WT   (OFF_TOK + 736)          // 3552: scan temps (16)
#define OFF_NL   (OFF_WT + 16)            // 3568: nl[32][1024] = -log(clip(p)) [token][frame]
#define LDS_FLOATS (OFF_NL + NTOK*NLEN)   // 36336 floats = 145,344 B

__device__ __forceinline__ float min3f(float a, float b, float c) {
  return fminf(fminf(a, b), c);
}
// result[lane l] = src[l-1] for l>=1; old[l] for lane 0 (wave_shr:1, bound_ctrl=false)
__device__ __forceinline__ float dpp_shr1(float old_v, float src) {
  return __int_as_float(__builtin_amdgcn_update_dpp(
      __float_as_int(old_v), __float_as_int(src), 0x138, 0xF, 0xF, false));
}

// One iteration = 8 row-slots. Lane l at slot s computes DP row r = c*128 + (s-l) + 1
// over its 4 columns J+1..J+4 (J = 256*wv + 4*lane). V[r][J+1+cc] update:
//   m_cc = min3( diag + sub, up + 1, left + ins )
// diag chain via dgL (lane l-1 right edge, prev row), left via DPP each slot.
template <bool MASKED>
__device__ __forceinline__ void do_iter(
    int s0, int lane, int wv,
    const int* __restrict__ tokl, const float* __restrict__ nlJ,
    const float* __restrict__ bndR, float* __restrict__ bndW,
    int (&TKc)[8], float4 (&SBc)[8], int (&TKn)[8], float4 (&SBn)[8],
    float4 ri,
    float& vp0, float& vp1, float& vp2, float& vp3,
    float& dgL, float& m3p,
    float& wq0, float& wq1, float& wq2, float& wq3,
    float& ans, int qh)
{
  // prefetch tokens 16 slots ahead, subs 8 slots ahead (using tokens read last iter)
#pragma unroll
  for (int k = 0; k < 8; ++k) TKn[k] = tokl[s0 + 16 + k];
#pragma unroll
  for (int k = 0; k < 8; ++k)
    SBn[k] = *(const float4*)(nlJ + ((size_t)((unsigned)TKc[k]) << 10));
  // boundary inject stream (lane-uniform reads; only lane 0's value is consumed)
  float4 ja = *(const float4*)(bndR + s0);
  float4 jb = *(const float4*)(bndR + s0 + 4);
  float inj[8] = {ja.x, ja.y, ja.z, ja.w, jb.x, jb.y, jb.z, jb.w};
  const int q0 = s0 - lane;
#pragma unroll
  for (int k = 0; k < 8; ++k) {
    const int q = q0 + k;
    float Lnow = dpp_shr1(inj[k], m3p);   // V[r][J] from lane l-1 (or boundary on lane 0)
    float m0 = min3f(dgL + SBc[k].x, vp0 + 1.0f, Lnow + ri.x);
    float m1 = min3f(vp0 + SBc[k].y, vp1 + 1.0f, m0 + ri.y);
    float m2 = min3f(vp1 + SBc[k].z, vp2 + 1.0f, m1 + ri.z);
    float m3 = min3f(vp2 + SBc[k].w, vp3 + 1.0f, m2 + ri.w);
    if (MASKED) {
      bool act = ((unsigned)q) < 128u;
      bool lt  = (q < 128);
      dgL = lt ? Lnow : dgL;
      vp0 = act ? m0 : vp0;  vp1 = act ? m1 : vp1;
      vp2 = act ? m2 : vp2;  vp3 = act ? m3 : vp3;
      m3p = act ? m3 : m3p;
      if (act && q == qh) ans = m3;
    } else {
      dgL = Lnow; vp0 = m0; vp1 = m1; vp2 = m2; vp3 = m3; m3p = m3;
      if (q == qh) ans = m3;
    }
    // rolling export regs; index (k+1)&3 == (lane63's q)&3, compile-time
    switch ((k + 1) & 3) {
      case 0: wq0 = m3; break; case 1: wq1 = m3; break;
      case 2: wq2 = m3; break; case 3: wq3 = m3; break;
    }
    if (k == 2 || k == 6) {
      int q63 = s0 + k - 63;
      if (wv < 3 && lane == 63 && q63 >= 3 && q63 < 128)
        *(float4*)(bndW + (q63 - 3)) = make_float4(wq0, wq1, wq2, wq3);
    }
  }
}

__global__ __launch_bounds__(256, 1) void align_loss_kernel(
    const int* __restrict__ y_true, const float* __restrict__ y_pred,
    float* __restrict__ partial)
{
  extern __shared__ float smem[];
  float* P0    = smem + OFF_P0;
  float* bnd   = smem + OFF_BND;
  float* bndZ  = smem + OFF_BNDZ;
  int*   tokbuf= (int*)(smem + OFF_TOK);
  int*   tokg  = tokbuf + 64;           // real tokens at [0,512), guarded both sides
  float* wtmp  = smem + OFF_WT;
  int*   wti   = (int*)wtmp;
  float* nl    = smem + OFF_NL;

  const int b = blockIdx.x;
  const int t = threadIdx.x;
  const int lane = t & 63;
  const int wv = t >> 6;

  // ---- zero token buffer (incl. guards) ----
  for (int idx = t; idx < 736; idx += 256) tokbuf[idx] = 0;
  __syncthreads();

  // ---- Phase A: left-shift compaction (2 halves of 256) ----
  int total = 0;
  for (int h = 0; h < 2; ++h) {
    int yt = y_true[b * MLEN + h * 256 + t];
    bool f = (yt != PADT);
    unsigned long long m = __ballot(f);
    int wp = __popcll(m & ((1ull << lane) - 1ull));
    if (lane == 0) wti[8 + wv] = __popcll(m);
    __syncthreads();
    int offs = total, ht = 0;
#pragma unroll
    for (int w2 = 0; w2 < NWAVE; ++w2) { int cnt = wti[8 + w2]; if (w2 < wv) offs += cnt; ht += cnt; }
    if (f) tokg[offs + wp] = yt;
    total += ht;
    __syncthreads();
  }
  const int L = total;

  // ---- Phase B: nl[tk][r] = -log(clip(y_pred[b,r,tk]/sum)) ----
  for (int r = t; r < NLEN; r += 256) {
    const float4* rp = (const float4*)(y_pred + ((size_t)b * NLEN + r) * NTOK);
    float4 q[8]; float s = 0.f;
#pragma unroll
    for (int u = 0; u < 8; ++u) { q[u] = rp[u]; s += q[u].x + q[u].y + q[u].z + q[u].w; }
    float inv = 1.0f / s;
#pragma unroll
    for (int u = 0; u < 8; ++u) {
      float pv[4] = {q[u].x, q[u].y, q[u].z, q[u].w};
#pragma unroll
      for (int c2 = 0; c2 < 4; ++c2) {
        float p = pv[c2] * inv;
        p = fminf(fmaxf(p, EPS_F), 1.0f - EPS_F);
        nl[(u * 4 + c2) * NLEN + r] = -__logf(p);
      }
    }
  }
  __syncthreads();

  // ---- Row-0 prefix: P0[m] = V[0][m+1] = sum_{r<=m} ins[r] ----
  {
    float4 iv = *(const float4*)(nl + PADT * NLEN + 4 * t);
    float p1 = iv.x, p2 = iv.x + iv.y, p3 = p2 + iv.z, s4 = p3 + iv.w;
    float x = s4;
#pragma unroll
    for (int d = 1; d < 64; d <<= 1) {
      float y = __shfl_up(x, d);
      if (lane >= d) x += y;
    }
    if (lane == 63) wtmp[wv] = x;
    __syncthreads();
    float pre = x - s4;
#pragma unroll
    for (int w2 = 0; w2 < NWAVE; ++w2) if (w2 < wv) pre += wtmp[w2];
    *(float4*)(P0 + 4 * t) = make_float4(pre + p1, pre + p2, pre + p3, pre + s4);
  }
  __syncthreads();

  // ---- per-lane persistent DP state ----
  const int J = 256 * wv + 4 * lane;      // lane owns DP cols J+1..J+4 (frames J..J+3)
  const float* nlJ = nl + J;
  float4 ri = *(const float4*)(nl + PADT * NLEN + J);   // ins costs, registers forever
  float4 vpi = *(const float4*)(P0 + J);                // V[0][J+1..J+4]
  float vp0 = vpi.x, vp1 = vpi.y, vp2 = vpi.z, vp3 = vpi.w;
  float m3p = vp3;                                      // right edge at row 0
  float dgL = 0.0f;
  if (J > 0) dgL = P0[J - 1];                           // V[0][J]
  float wq0 = 0, wq1 = 0, wq2 = 0, wq3 = 0, ans = 0.0f;

  // ---- transposed systolic phases ----
  for (int p = 0; p < NPHASE; ++p) {
    __syncthreads();
    const int c = p - wv;
    if (c < 0 || c >= NC) continue;
    const int* tokl = tokg + c * RCH - lane;
    const float* bndR = (wv == 0) ? bndZ : (bnd + ((wv - 1) * 2 + (c & 1)) * 256);
    float* bndW = bnd + (wv * 2 + (c & 1)) * 256;
    const int qh = L - 1 - c * RCH;
    if (wv == 0) {
      float base = (float)(c * RCH + 1);
      bndZ[lane]       = base + (float)lane;
      bndZ[lane + 64]  = base + (float)(lane + 64);
      bndZ[lane + 128] = base + (float)(lane + 128);
      bndZ[lane + 192] = base + (float)(lane + 192);
    }
    // prime pipeline: subs for slots 0..7, tokens for slots 8..15
    int tk0[8], TKa[8], TKb[8]; float4 SBa[8], SBb[8];
#pragma unroll
    for (int k = 0; k < 8; ++k) tk0[k] = tokl[k];
#pragma unroll
    for (int k = 0; k < 8; ++k) SBa[k] = *(const float4*)(nlJ + ((size_t)((unsigned)tk0[k]) << 10));
#pragma unroll
    for (int k = 0; k < 8; ++k) TKa[k] = tokl[8 + k];

    int s0 = 0;
    for (int pr = 0; pr < 4; ++pr) {   // iters 0..7 (masked ramp-in)
      do_iter<true>(s0, lane, wv, tokl, nlJ, bndR, bndW, TKa, SBa, TKb, SBb, ri,
                    vp0, vp1, vp2, vp3, dgL, m3p, wq0, wq1, wq2, wq3, ans, qh); s0 += 8;
      do_iter<true>(s0, lane, wv, tokl, nlJ, bndR, bndW, TKb, SBb, TKa, SBa, ri,
                    vp0, vp1, vp2, vp3, dgL, m3p, wq0, wq1, wq2, wq3, ans, qh); s0 += 8;
    }
    for (int pr = 0; pr < 4; ++pr) {   // iters 8..15 (all lanes active)
      do_iter<false>(s0, lane, wv, tokl, nlJ, bndR, bndW, TKa, SBa, TKb, SBb, ri,
                     vp0, vp1, vp2, vp3, dgL, m3p, wq0, wq1, wq2, wq3, ans, qh); s0 += 8;
      do_iter<false>(s0, lane, wv, tokl, nlJ, bndR, bndW, TKb, SBb, TKa, SBa, ri,
                     vp0, vp1, vp2, vp3, dgL, m3p, wq0, wq1, wq2, wq3, ans, qh); s0 += 8;
    }
    for (int pr = 0; pr < 4; ++pr) {   // iters 16..23 (masked ramp-out)
      do_iter<true>(s0, lane, wv, tokl, nlJ, bndR, bndW, TKa, SBa, TKb, SBb, ri,
                    vp0, vp1, vp2, vp3, dgL, m3p, wq0, wq1, wq2, wq3, ans, qh); s0 += 8;
      do_iter<true>(s0, lane, wv, tokl, nlJ, bndR, bndW, TKb, SBb, TKa, SBa, ri,
                    vp0, vp1, vp2, vp3, dgL, m3p, wq0, wq1, wq2, wq3, ans, qh); s0 += 8;
    }
  }

  // ---- extract D[L][1024] = right edge (lane 255's m3) at row L ----
  if (t == 255) partial[b] = ans;
  if (L == 0 && t == 0) partial[b] = P0[NLEN - 1];
}

__global__ void reduce_kernel(const float* __restrict__ partial, float* __restrict__ out) {
  if (threadIdx.x == 0) {
    float s = 0.f;
    for (int b2 = 0; b2 < 32; ++b2) s += partial[b2];
    out[0] = s;
  }
}

extern "C" void kernel_launch(void* const* d_in, const int* in_sizes, int n_in,
                              void* d_out, int out_size, void* d_ws, size_t ws_size,
                              hipStream_t stream) {
  const int*   y_true = (const int*)d_in[0];
  const float* y_pred = (const float*)d_in[1];
  float* out = (float*)d_out;
  float* partial = (float*)d_ws;

  const size_t lds_bytes = (size_t)LDS_FLOATS * sizeof(float);
  hipFuncSetAttribute((const void*)align_loss_kernel,
                      hipFuncAttributeMaxDynamicSharedMemorySize, (int)lds_bytes);

  hipLaunchKernelGGL(align_loss_kernel, dim3(32), dim3(256), lds_bytes, stream,
                     y_true, y_pred, partial);
  hipLaunchKernelGGL(reduce_kernel, dim3(1), dim3(64), 0, stream, partial, out);
}